// Round 9
// baseline (14613.223 us; speedup 1.0000x reference)
//
#include <hip/hip_runtime.h>

// ---------------------------------------------------------------------------
// Graves handwriting synthesis: 3x peephole-LSTM(400) + soft window attention
// + MDN head.  B=32, T=400.  Persistent kernel.
//
// Round 13 = round 8 chassis (7.14 ms) + occupancy doubling:
//  * Diagnosis: stable 7.6ms = ~7us issue + ~2.5us barrier + ~9us EXPOSED
//    latency/step.  1 block/CU (71.6KB weights) = 4 waves/SIMD cannot hide
//    it; in-block pipelining (r11) was already futile.  Lever = 8 waves/SIMD.
//  * 400 compute blocks x 4 columns (1 unit x 4 gates): weights 35.8KB,
//    block LDS ~72KB -> 2 blocks/CU, 32 waves/CU.  416 blocks co-resident
//    (<= 512 capacity).  amdgpu_waves_per_eu(8,8) pins the 64-VGPR budget
//    (already met at 64) -> residency compile-time safe.
//  * K split 8 ways {52x7,36} (16B-aligned float4 segments); kq = tid>>7 is
//    wave-uniform.  Bank math: 4-col b128 weight reads (stride 2236) and
//    stride-73 wstg reads both conflict-free.
//  * Attention (8 blocks, glob-poll pacing), wcnt w-publication, compute
//    barrier (8 groups x 50), finalize order, cross-block state scheme all
//    UNCHANGED (verified): fp32 write-once rotating slots, relaxed
//    agent-scope write-through stores, relaxed-only two-level barrier.
// ---------------------------------------------------------------------------

#define NATT   8
#define NBLKC  400
#define NBLK   408    // 8 attention + 400 compute
#define NTHR   1024
#define TSTEPS 400
#define BATCH  32
#define UNITSN 400
#define NCHARS 73
#define UC     50
#define KTOT   2228   // 476 (z1) + 876 (z2) + 876 (z3)
#define WSTR   2236   // LDS weight row stride; %32=28 -> 4 cols distinct banks
#define NGRP   8
#define NFLAG  32
#define NEPOCH 402    // 1 prologue + 400 steps + 1 epilogue

typedef unsigned int       u32;
typedef unsigned long long u64;

// ---- ws byte layout ----
// [0,4096): barrier ints (memset to 0 each launch)
//   grp_cnt[g] at int g*16 (g<8); glob_cnt at int 128; wcnt at int 192;
//   flags[f] at int 256+f*16
#define STATE_BYTES 4096
#define HSLOT     12832                           // fp32 elems/slot (12800+32 pad)
#define H1_BYTE   4096
#define H2_BYTE   (H1_BYTE + TSTEPS * HSLOT * 4)
#define H3_BYTE   (H2_BYTE + TSTEPS * HSLOT * 4)
#define WSLOT     2368                            // fp32 elems/slot (2336+32 pad)
#define WH_BYTE   (H3_BYTE + TSTEPS * HSLOT * 4)
// end of ws usage: WH_BYTE + 400*WSLOT*4 = 65,386,496 bytes (~62 MB)

__device__ __forceinline__ float sigf(float x)   { return 1.0f / (1.0f + __expf(-x)); }
__device__ __forceinline__ float tanhf_(float x) { return 1.0f - 2.0f / (1.0f + __expf(2.0f * x)); }

// single N4*4-float dot: w from LDS, x from global
template<int N4>
__device__ __forceinline__ float dotX(const float* __restrict__ w,
                                      const float* __restrict__ x) {
  const float4* wv = (const float4*)w;
  const float4* xv = (const float4*)x;
  float s0 = 0.f, s1 = 0.f, s2 = 0.f, s3 = 0.f;
#pragma unroll
  for (int i = 0; i < N4; ++i) {
    float4 a = wv[i], bb = xv[i];
    s0 = fmaf(a.x, bb.x, s0); s1 = fmaf(a.y, bb.y, s1);
    s2 = fmaf(a.z, bb.z, s2); s3 = fmaf(a.w, bb.w, s3);
  }
  return (s0 + s1) + (s2 + s3);
}

// dual dot sharing one x stream
template<int N4>
__device__ __forceinline__ void dotX2(const float* __restrict__ wa,
                                      const float* __restrict__ wb,
                                      const float* __restrict__ x,
                                      float& ra, float& rb) {
  const float4* av = (const float4*)wa;
  const float4* bv = (const float4*)wb;
  const float4* xv = (const float4*)x;
  float a0 = 0.f, a1 = 0.f, a2 = 0.f, a3 = 0.f;
  float c0 = 0.f, c1 = 0.f, c2 = 0.f, c3 = 0.f;
#pragma unroll
  for (int i = 0; i < N4; ++i) {
    float4 xx = xv[i], aa = av[i], bb = bv[i];
    a0 = fmaf(aa.x, xx.x, a0); a1 = fmaf(aa.y, xx.y, a1);
    a2 = fmaf(aa.z, xx.z, a2); a3 = fmaf(aa.w, xx.w, a3);
    c0 = fmaf(bb.x, xx.x, c0); c1 = fmaf(bb.y, xx.y, c1);
    c2 = fmaf(bb.z, xx.z, c2); c3 = fmaf(bb.w, xx.w, c3);
  }
  ra += (a0 + a1) + (a2 + a3);
  rb += (c0 + c1) + (c2 + c3);
}

// fused P-phase dots (t>=2): three x streams (h2p, h1t, h3pp), five weight
// streams.  r3 += wA.x2 + wE.x3, r2 += wB.x2 + wC.x1, r1 += wD.x1.
template<int N4>
__device__ __forceinline__ void dotP3(const float* __restrict__ wA,
                                      const float* __restrict__ wB,
                                      const float* __restrict__ x2,
                                      const float* __restrict__ wC,
                                      const float* __restrict__ wD,
                                      const float* __restrict__ x1,
                                      const float* __restrict__ wE,
                                      const float* __restrict__ x3,
                                      float& r3, float& r2, float& r1) {
  const float4* Av = (const float4*)wA;
  const float4* Bv = (const float4*)wB;
  const float4* Cv = (const float4*)wC;
  const float4* Dv = (const float4*)wD;
  const float4* Ev = (const float4*)wE;
  const float4* x2v = (const float4*)x2;
  const float4* x1v = (const float4*)x1;
  const float4* x3v = (const float4*)x3;
  float sA0 = 0.f, sA1 = 0.f, sA2 = 0.f, sA3 = 0.f;
  float sB0 = 0.f, sB1 = 0.f, sB2 = 0.f, sB3 = 0.f;
  float sC0 = 0.f, sC1 = 0.f, sC2 = 0.f, sC3 = 0.f;
  float sD0 = 0.f, sD1 = 0.f, sD2 = 0.f, sD3 = 0.f;
  float sE0 = 0.f, sE1 = 0.f, sE2 = 0.f, sE3 = 0.f;
#pragma unroll 2
  for (int i = 0; i < N4; ++i) {
    float4 xa = x2v[i], xb = x1v[i], xc = x3v[i];
    float4 a = Av[i], bb = Bv[i], cc = Cv[i], d = Dv[i], e = Ev[i];
    sA0 = fmaf(a.x, xa.x, sA0);  sA1 = fmaf(a.y, xa.y, sA1);
    sA2 = fmaf(a.z, xa.z, sA2);  sA3 = fmaf(a.w, xa.w, sA3);
    sB0 = fmaf(bb.x, xa.x, sB0); sB1 = fmaf(bb.y, xa.y, sB1);
    sB2 = fmaf(bb.z, xa.z, sB2); sB3 = fmaf(bb.w, xa.w, sB3);
    sC0 = fmaf(cc.x, xb.x, sC0); sC1 = fmaf(cc.y, xb.y, sC1);
    sC2 = fmaf(cc.z, xb.z, sC2); sC3 = fmaf(cc.w, xb.w, sC3);
    sD0 = fmaf(d.x, xb.x, sD0);  sD1 = fmaf(d.y, xb.y, sD1);
    sD2 = fmaf(d.z, xb.z, sD2);  sD3 = fmaf(d.w, xb.w, sD3);
    sE0 = fmaf(e.x, xc.x, sE0);  sE1 = fmaf(e.y, xc.y, sE1);
    sE2 = fmaf(e.z, xc.z, sE2);  sE3 = fmaf(e.w, xc.w, sE3);
  }
  r3 += (sA0 + sA1) + (sA2 + sA3) + (sE0 + sE1) + (sE2 + sE3);
  r2 += (sB0 + sB1) + (sB2 + sB3) + (sC0 + sC1) + (sC2 + sC3);
  r1 += (sD0 + sD1) + (sD2 + sD3);
}

// triple 73-float dot sharing one x stream (LDS), K-eighth split {9x7,10}
__device__ __forceinline__ void dot73x3(const float* __restrict__ w1,
                                        const float* __restrict__ w2,
                                        const float* __restrict__ w3,
                                        const float* __restrict__ x, int kq,
                                        float& r1, float& r2, float& r3) {
  int st = kq * 9;
  int en = st + ((kq == 7) ? 10 : 9);
  float s1 = 0.f, s2 = 0.f, s3 = 0.f;
  for (int k = st; k < en; ++k) {
    float xv = x[k];
    s1 = fmaf(w1[k], xv, s1); s2 = fmaf(w2[k], xv, s2); s3 = fmaf(w3[k], xv, s3);
  }
  r1 += s1; r2 += s2; r3 += s3;
}

extern "C" __global__ void __launch_bounds__(NTHR)
__attribute__((amdgpu_waves_per_eu(8, 8)))
hand_kernel(const float* __restrict__ xs, const int* __restrict__ chars,
            const int* __restrict__ lens,
            const float* __restrict__ Wx0, const float* __restrict__ Wh0,
            const float* __restrict__ b0, const float* __restrict__ p0,
            const float* __restrict__ Wx1, const float* __restrict__ Wh1,
            const float* __restrict__ b1, const float* __restrict__ p1,
            const float* __restrict__ Wx2, const float* __restrict__ Wh2,
            const float* __restrict__ b2, const float* __restrict__ p2,
            const float* __restrict__ Watt, const float* __restrict__ batt,
            const float* __restrict__ Wmdn, const float* __restrict__ bmdn,
            float* __restrict__ dout, char* __restrict__ wsb) {
  const int blk = blockIdx.x;
  const int tid = threadIdx.x;
  const bool is_att = (blk < NATT);
  const int cblk = blk - NATT;        // compute block index 0..399

  // compute: first 4*WSTR floats = 4 weight columns (35.8KB)
  // attention: Watt[12000] + attp[960] partials (51.8KB)
  __shared__ __align__(16) float wlw[12960];
  __shared__ float zpart[NTHR], zpartB[NTHR];
  __shared__ float zbuf[128], zbufB[128];
  __shared__ float biasL[3][4];
  __shared__ float peepL[3][3];
  __shared__ float cstate[3][32];     // [layer][batch]
  __shared__ int   bar_target;
  __shared__ float alphaL[40], betaL[40], kappaL[40];   // attention (4 batches)
  __shared__ float wlds[4 * NCHARS];                    // attention w slice
  __shared__ __align__(16) float wstg[BATCH * NCHARS + 12];  // compute: staged w(t)

  int*   bar_i = (int*)wsb;
  int*   glob  = bar_i + 128;
  int*   wcnt  = bar_i + 192;
  float* h1h   = (float*)(wsb + H1_BYTE);
  float* h2h   = (float*)(wsb + H2_BYTE);
  float* h3h   = (float*)(wsb + H3_BYTE);
  float* whh   = (float*)(wsb + WH_BYTE);

  const int out = tid & 127;
  const int b   = out >> 2;    // batch 0..31
  const int c   = out & 3;     // gate (i,f,g,o)
  const int kq  = tid >> 7;    // k-eighth 0..7 (wave-uniform: kq = wave/2)
  const int u0  = cblk;        // this block's unit column 0..399
  const int ko  = kq * 52;     // h-segment start (52x7 + 36; 16B-aligned)

  if (tid == 0) bar_target = 0;
  if (tid < 96) cstate[tid / 32][tid % 32] = 0.f;
  if (tid < 40) kappaL[tid] = 0.f;

  // ---- one-time staging ----
  if (!is_att) {
    // compute: 4 weight columns into LDS
    for (int idx = tid; idx < 4 * KTOT; idx += NTHR) {
      int cc = idx / KTOT, k = idx - cc * KTOT;
      int gcol = cc * UNITSN + u0;
      float v;
      if (k < 476)        v = (k < 76)  ? Wx0[(size_t)k * 1600 + gcol]
                                        : Wh0[(size_t)(k - 76) * 1600 + gcol];
      else if (k < 1352) { int q = k - 476;
                          v = (q < 476) ? Wx1[(size_t)q * 1600 + gcol]
                                        : Wh1[(size_t)(q - 476) * 1600 + gcol]; }
      else               { int q = k - 1352;
                          v = (q < 476) ? Wx2[(size_t)q * 1600 + gcol]
                                        : Wh2[(size_t)(q - 476) * 1600 + gcol]; }
      wlw[cc * WSTR + k] = v;
    }
    if (tid < 12) {
      int l = tid >> 2, cc = tid & 3;
      const float* bs = (l == 0) ? b0 : (l == 1) ? b1 : b2;
      biasL[l][cc] = bs[cc * UNITSN + u0];
    }
    if (tid < 9) {
      int l = tid / 3, r = tid - l * 3;
      const float* ps = (l == 0) ? p0 : (l == 1) ? p1 : p2;
      peepL[l][r] = ps[r * UNITSN + u0];
    }
  } else {
    // attention: Watt[400][30] into LDS (reused all 400 steps)
    for (int i = tid; i < 12000; i += NTHR) wlw[i] = Watt[i];
  }
  __syncthreads();

  const float* Wc   = wlw + c * WSTR;   // compute: this thread's column
  float*       attp = wlw + 12000;      // attention: 960 partials

  // ---- compute-only two-level grid barrier (flag release; verified) ----
  auto gridbar = [&]() {
    __syncthreads();
    if (tid == 0) {
      int e = ++bar_target;
      int g = cblk & (NGRP - 1);
      const int gsz = NBLKC / NGRP;                  // 50 exactly
      int a = __hip_atomic_fetch_add(bar_i + g * 16, 1, __ATOMIC_RELAXED, __HIP_MEMORY_SCOPE_AGENT);
      if (a + 1 == e * gsz) {                        // last of my group this epoch
        int q = __hip_atomic_fetch_add(glob, 1, __ATOMIC_RELAXED, __HIP_MEMORY_SCOPE_AGENT);
        if (((q + 1) & (NGRP - 1)) == 0) {           // last group: release all
          for (int f = 0; f < NFLAG; ++f)
            __hip_atomic_store(bar_i + 256 + f * 16, e, __ATOMIC_RELAXED, __HIP_MEMORY_SCOPE_AGENT);
        }
      }
      int* myflag = bar_i + 256 + (cblk & (NFLAG - 1)) * 16;
      while (__hip_atomic_load(myflag, __ATOMIC_RELAXED, __HIP_MEMORY_SCOPE_AGENT) < e)
        __builtin_amdgcn_s_sleep(2);
    }
    __syncthreads();
  };

  // attention-side wait: poll the glob group-counter (8 pollers only)
  auto waitglob = [&](int e) {
    if (tid == 0) {
      int tgt = NGRP * e;
      while (__hip_atomic_load(glob, __ATOMIC_RELAXED, __HIP_MEMORY_SCOPE_AGENT) < tgt)
        __builtin_amdgcn_s_sleep(2);
    }
    __syncthreads();
  };

  // gate math for one layer, 1 unit, one 4B write-through store
  auto gates = [&](int layer, const float* zb, int bb, float* hdst) {
    float zi = zb[bb * 4 + 0], zf = zb[bb * 4 + 1];
    float zg = zb[bb * 4 + 2], zo = zb[bb * 4 + 3];
    float cold = cstate[layer][bb];
    float ig = sigf(zi + peepL[layer][0] * cold);
    float fg = sigf(zf + peepL[layer][1] * cold);
    float cn = fg * cold + ig * tanhf_(zg);
    float og = sigf(zo + peepL[layer][2] * cn);
    cstate[layer][bb] = cn;
    __hip_atomic_store(hdst + bb * UNITSN + u0, og * tanhf_(cn),
                       __ATOMIC_RELAXED, __HIP_MEMORY_SCOPE_AGENT);
  };

  // single-layer finalize; NO trailing sync
  auto finalize1 = [&](int layer, float acc, float* hdst) {
    zpart[tid] = acc;
    __syncthreads();
    if (tid < 128) {
      float s = biasL[layer][tid & 3];
#pragma unroll
      for (int m = 0; m < 8; ++m) s += zpart[tid + m * 128];
      zbuf[tid] = s;
    }
    __syncthreads();
    if (tid < 128 && (tid & 3) == 0) gates(layer, zbuf, tid >> 2, hdst);
  };

  // merged Q finalize: h2(t) and (optionally) h1(t+1); NO trailing sync
  auto finalizeQ = [&](float a2v, float* h2dst, float a1v, float* h1dst, bool do1) {
    zpart[tid]  = a2v;
    zpartB[tid] = a1v;
    __syncthreads();
    if (tid < 128) {
      float s2 = biasL[1][tid & 3], s1 = biasL[0][tid & 3];
#pragma unroll
      for (int m = 0; m < 8; ++m) {
        s2 += zpart[tid + m * 128];
        s1 += zpartB[tid + m * 128];
      }
      zbuf[tid]  = s2;
      zbufB[tid] = s1;
    }
    __syncthreads();
    if (tid < 128 && (tid & 3) == 0) {
      gates(1, zbuf, tid >> 2, h2dst);
      if (do1) gates(0, zbufB, tid >> 2, h1dst);
    }
  };

  // ============================ ATTENTION PATH ============================
  if (is_att) {
    const int bs0 = blk * 4;
    for (int t = 0; t < TSTEPS; ++t) {
      waitglob(t + 1);                       // h1(t) certified by epoch t+1
      const float* h1g = h1h + (size_t)t * HSLOT;
      float* wdst = whh + (size_t)t * WSLOT + bs0 * NCHARS;
      for (int i = tid; i < 4 * NCHARS; i += NTHR) wlds[i] = 0.f;
      // stage B: 2b x 2j x 8ks register tile; h float2-vectorized
      if (tid < 240) {
        int ks = tid / 30, r = tid - ks * 30;
        int bb2 = r / 15, jj2 = r - bb2 * 15;
        int j0 = 2 * jj2, j1 = j0 + 1;
        const float2* h0v = (const float2*)(h1g + (bs0 + 2 * bb2) * UNITSN + ks * 50);
        const float2* h1v = (const float2*)(h1g + (bs0 + 2 * bb2 + 1) * UNITSN + ks * 50);
        const float* wv = wlw + (ks * 50) * 30;
        float s00 = 0.f, s01 = 0.f, s10 = 0.f, s11 = 0.f;
#pragma unroll
        for (int kk = 0; kk < 25; ++kk) {
          float2 ha = h0v[kk], hb = h1v[kk];
          float wa0 = wv[(2 * kk) * 30 + j0],     wb0 = wv[(2 * kk) * 30 + j1];
          float wa1 = wv[(2 * kk + 1) * 30 + j0], wb1 = wv[(2 * kk + 1) * 30 + j1];
          s00 = fmaf(ha.x, wa0, s00); s01 = fmaf(ha.x, wb0, s01);
          s10 = fmaf(hb.x, wa0, s10); s11 = fmaf(hb.x, wb0, s11);
          s00 = fmaf(ha.y, wa1, s00); s01 = fmaf(ha.y, wb1, s01);
          s10 = fmaf(hb.y, wa1, s10); s11 = fmaf(hb.y, wb1, s11);
        }
        int b0i = 2 * bb2;
        attp[(b0i * 30 + j0) * 8 + ks] = s00;
        attp[(b0i * 30 + j1) * 8 + ks] = s01;
        attp[((b0i + 1) * 30 + j0) * 8 + ks] = s10;
        attp[((b0i + 1) * 30 + j1) * 8 + ks] = s11;
      }
      __syncthreads();
      // reduce 8 partials + transforms (40 threads: bl 0..3, j 0..9)
      if (tid < 40) {
        int bl = tid / 10, j = tid - bl * 10;
        float ah = batt[j], bh = batt[10 + j], kh = batt[20 + j];
#pragma unroll
        for (int s = 0; s < 8; ++s) {
          ah += attp[(bl * 30 + j) * 8 + s];
          bh += attp[(bl * 30 + 10 + j) * 8 + s];
          kh += attp[(bl * 30 + 20 + j) * 8 + s];
        }
        float kap = kappaL[tid] + __expf(kh);
        kappaL[tid] = kap;
        alphaL[tid] = __expf(ah);
        betaL[tid]  = __expf(bh);
      }
      __syncthreads();
      // phi + soft window scatter (200 items, few LDS atomics)
      if (tid < 4 * UC) {
        int bl = tid / UC, u = tid - bl * UC;
        if (u < lens[bs0 + bl]) {
          float ph = 0.f;
#pragma unroll
          for (int j = 0; j < 10; ++j) {
            float d = kappaL[bl * 10 + j] - (float)u;
            ph = fmaf(alphaL[bl * 10 + j], __expf(-betaL[bl * 10 + j] * d * d), ph);
          }
          atomicAdd(&wlds[bl * NCHARS + chars[(bs0 + bl) * UC + u]], ph);
        }
      }
      __syncthreads();
      // write w slice (292 floats = 146 u64 write-through stores)
      for (int i = tid; i < (4 * NCHARS) / 2; i += NTHR) {
        union { float f[2]; u64 v; } pk;
        pk.f[0] = wlds[2 * i]; pk.f[1] = wlds[2 * i + 1];
        __hip_atomic_store((u64*)(wdst + 2 * i), pk.v,
                           __ATOMIC_RELAXED, __HIP_MEMORY_SCOPE_AGENT);
      }
      __syncthreads();   // drain all waves' write-through stores
      if (tid == 0)
        __hip_atomic_fetch_add(wcnt, 1, __ATOMIC_RELAXED, __HIP_MEMORY_SCOPE_AGENT);
    }
    waitglob(NEPOCH);    // h3(T-1) certified before MDN
  }
  // ============================ COMPUTE PATH =============================
  else {
    // prologue: h1(0) from x(0) only -> h1 slot 0
    {
      float acc = 0.f;
      if (kq == 0) {
        const float* xr = xs + (size_t)b * TSTEPS * 3;
        acc = Wc[0] * xr[0] + Wc[1] * xr[1] + Wc[2] * xr[2];
      }
      finalize1(0, acc, h1h);
    }
    gridbar();                                        // epoch 1

    float acc_z3 = 0.f;
    for (int t = 0; t < TSTEPS; ++t) {
      const float* h1t  = h1h + (size_t)t * HSLOT + b * UNITSN;
      const float* h2p  = h2h + (size_t)(t > 0 ? t - 1 : 0) * HSLOT + b * UNITSN;
      const float* h3pp = h3h + (size_t)(t > 1 ? t - 2 : 0) * HSLOT + b * UNITSN;
      // ---- P: h-dots (kq wave-uniform -> no divergence) ----
      float a3f = acc_z3, a2 = 0.f, a1 = 0.f;
      if (t >= 2) {
        if (kq < 7)
          dotP3<13>(Wc + 1428 + ko, Wc + 952 + ko, h2p + ko,
                    Wc + 552 + ko,  Wc + 76 + ko,  h1t + ko,
                    Wc + 1828 + ko, h3pp + ko, a3f, a2, a1);
        else
          dotP3<9>(Wc + 1428 + ko, Wc + 952 + ko, h2p + ko,
                   Wc + 552 + ko,  Wc + 76 + ko,  h1t + ko,
                   Wc + 1828 + ko, h3pp + ko, a3f, a2, a1);
      } else if (t == 1) {
        if (kq < 7) {
          dotX2<13>(Wc + 1428 + ko, Wc + 952 + ko, h2p + ko, a3f, a2);
          dotX2<13>(Wc + 552 + ko, Wc + 76 + ko, h1t + ko, a2, a1);
        } else {
          dotX2<9>(Wc + 1428 + ko, Wc + 952 + ko, h2p + ko, a3f, a2);
          dotX2<9>(Wc + 552 + ko, Wc + 76 + ko, h1t + ko, a2, a1);
        }
      } else {
        if (kq < 7) dotX2<13>(Wc + 552 + ko, Wc + 76 + ko, h1t + ko, a2, a1);
        else        dotX2<9>(Wc + 552 + ko, Wc + 76 + ko, h1t + ko, a2, a1);
      }
      if (kq == 0) {
        const float* xr = xs + ((size_t)b * TSTEPS + t) * 3;
        a2 += Wc[476] * xr[0] + Wc[477] * xr[1] + Wc[478] * xr[2];
        if (t < TSTEPS - 1)
          a1 += Wc[0] * xr[3] + Wc[1] * xr[4] + Wc[2] * xr[5];
      }
      // finalize h3(t-1) here: overlaps the w-wait window (round-6 ordering)
      if (t > 0) finalize1(2, a3f, h3h + (size_t)(t - 1) * HSLOT);
      // ---- wait for w(t) (monotone counter) ----
      if (tid == 0) {
        int tgt = NATT * (t + 1);
        while (__hip_atomic_load(wcnt, __ATOMIC_RELAXED, __HIP_MEMORY_SCOPE_AGENT) < tgt)
          __builtin_amdgcn_s_sleep(2);
      }
      __syncthreads();
      // ---- stage w(t) into LDS (584 coalesced float4) ----
      {
        const float4* wsrc = (const float4*)(whh + (size_t)t * WSLOT);
        for (int i = tid; i < (BATCH * NCHARS) / 4; i += NTHR)
          ((float4*)wstg)[i] = wsrc[i];
      }
      __syncthreads();
      // ---- Q: w-dots + finalize h2(t), h1(t+1) ----
      bool do1 = (t < TSTEPS - 1);
      float q2 = a2, q1 = a1, z3n = 0.f;
      dot73x3(Wc + 479, Wc + 3, Wc + 1355, wstg + b * NCHARS, kq, q2, q1, z3n);
      if (kq == 0) {
        const float* xr = xs + ((size_t)b * TSTEPS + t) * 3;
        z3n += Wc[1352] * xr[0] + Wc[1353] * xr[1] + Wc[1354] * xr[2];
      }
      finalizeQ(q2, h2h + (size_t)t * HSLOT,
                q1, h1h + (size_t)(t + 1) * HSLOT, do1);
      acc_z3 = z3n;
      gridbar();                                      // epoch t+2
    }
    // epilogue: finish z3(T-1) -> h3 slot T-1
    {
      const float* h2l  = h2h + (size_t)(TSTEPS - 1) * HSLOT + b * UNITSN;
      const float* h3ll = h3h + (size_t)(TSTEPS - 2) * HSLOT + b * UNITSN;
      float a3 = acc_z3;
      if (kq < 7) a3 += dotX<13>(Wc + 1428 + ko, h2l + ko)
                      + dotX<13>(Wc + 1828 + ko, h3ll + ko);
      else        a3 += dotX<9>(Wc + 1428 + ko, h2l + ko)
                      + dotX<9>(Wc + 1828 + ko, h3ll + ko);
      finalize1(2, a3, h3h + (size_t)(TSTEPS - 1) * HSLOT);
    }
    gridbar();                                        // epoch 402
  }

  // ---- MDN head + output transforms (12800 rows over 408 blocks) ----
  {
    int j = tid & 127, ks = tid >> 7;   // 8 k-slices of 50
    for (int i0 = 0; i0 < 32; i0 += 4) {
      float acc[4] = {0.f, 0.f, 0.f, 0.f};
      const float* hp[4];
      bool val[4];
      for (int r = 0; r < 4; ++r) {
        int row = blk + (i0 + r) * NBLK;
        val[r] = (row < 12800);
        hp[r] = val[r] ? (h3h + (size_t)(row % TSTEPS) * HSLOT + (row / TSTEPS) * UNITSN + ks * 50)
                       : h3h;
      }
      if (j < 121) {
        const float* wp = Wmdn + (size_t)(ks * 50) * 121 + j;
        for (int k = 0; k < 50; ++k) {
          float wv = wp[(size_t)k * 121];
#pragma unroll
          for (int r = 0; r < 4; ++r) acc[r] = fmaf(hp[r][k], wv, acc[r]);
        }
      }
      for (int r = 0; r < 4; ++r) {
        zpart[tid] = acc[r];
        __syncthreads();
        if (tid < 121) {
          float s = bmdn[tid];
#pragma unroll
          for (int m = 0; m < 8; ++m) s += zpart[tid + m * 128];
          zbufB[tid] = s;
        }
        __syncthreads();
        if (tid == 0) {
          float mx = zbufB[0];
          for (int q = 1; q < 20; ++q) mx = fmaxf(mx, zbufB[q]);
          float s = 0.f;
          for (int q = 0; q < 20; ++q) s += __expf(zbufB[q] - mx);
          zbufB[126] = mx;
          zbufB[127] = 1.f / s;
        }
        __syncthreads();
        if (val[r] && tid < 121) {
          int row = blk + (i0 + r) * NBLK;
          float y = zbufB[tid], o;
          if (tid < 20)       o = __expf(y - zbufB[126]) * zbufB[127];  // softmax(pi)
          else if (tid < 60)  o = y;                                    // mu1, mu2
          else if (tid < 100) o = __expf(y);                            // s1, s2
          else if (tid < 120) o = tanhf_(y);                            // rho
          else                o = sigf(y);                              // eos
          dout[(size_t)row * 121 + tid] = o;
        }
        __syncthreads();
      }
    }
  }
}

extern "C" void kernel_launch(void* const* d_in, const int* in_sizes, int n_in,
                              void* d_out, int out_size, void* d_ws, size_t ws_size,
                              hipStream_t stream) {
  const float* xs   = (const float*)d_in[0];
  const int*   chrs = (const int*)d_in[1];
  const int*   lens = (const int*)d_in[2];
  const float* Wx0  = (const float*)d_in[3];
  const float* Wh0  = (const float*)d_in[4];
  const float* b0   = (const float*)d_in[5];
  const float* p0   = (const float*)d_in[6];
  const float* Wx1  = (const float*)d_in[7];
  const float* Wh1  = (const float*)d_in[8];
  const float* b1   = (const float*)d_in[9];
  const float* p1   = (const float*)d_in[10];
  const float* Wx2  = (const float*)d_in[11];
  const float* Wh2  = (const float*)d_in[12];
  const float* b2   = (const float*)d_in[13];
  const float* p2   = (const float*)d_in[14];
  const float* Watt = (const float*)d_in[15];
  const float* batt = (const float*)d_in[16];
  const float* Wmdn = (const float*)d_in[17];
  const float* bmdn = (const float*)d_in[18];

  // zero barrier counters/flags + wcnt (4KB); everything else is write-once
  hipMemsetAsync(d_ws, 0, STATE_BYTES, stream);
  hipLaunchKernelGGL(hand_kernel, dim3(NBLK), dim3(NTHR), 0, stream,
                     xs, chrs, lens, Wx0, Wh0, b0, p0, Wx1, Wh1, b1, p1,
                     Wx2, Wh2, b2, p2, Watt, batt, Wmdn, bmdn,
                     (float*)d_out, (char*)d_ws);
}

// Round 10
// 7132.763 us; speedup vs baseline: 2.0487x; 2.0487x over previous
//
#include <hip/hip_runtime.h>

// ---------------------------------------------------------------------------
// Graves handwriting synthesis: 3x peephole-LSTM(400) + soft window attention
// + MDN head.  B=32, T=400.  Persistent kernel.
//
// Round 14 = ROUND 8 RESTORED (proven 7.14 ms best / 7.6 stable) + sleep(1).
//  * Round 13's occupancy doubling (400x1-unit blocks, 2 blocks/CU) REVERTED:
//    occupancy 40->78% but dur 7.1->14.6 ms.  Scalar 4B write-through h-stores
//    at 1600B stride caused partial-line RFO/invalidate at the LLC ->
//    FETCH 0.38->6.7 GB, WRITE 0.25->4.4 GB: the rotating state stopped being
//    cache-resident and every dependent h-read became an HBM miss.  Lesson:
//    state cache-residency > occupancy for this recurrence.
//  * Only change vs round 8: s_sleep(2) -> s_sleep(1) in the three poll loops
//    (finer wake granularity; each poller owns its own flag line).
//  * Structure (verified round 8): 200 compute blocks x 8 cols (2 units),
//    71.6KB LDS weights; 8 attention blocks paced by glob-counter polling
//    (start at last-arrival, not release); w(t) published via wcnt monotone
//    counter; compute-only two-level barrier (8 groups x 25, 32 flag lines);
//    fp32 write-once rotating slots, relaxed agent-scope write-through
//    stores, relaxed-only barrier, monotone epochs.
// ---------------------------------------------------------------------------

#define NATT   8
#define NBLK   208    // 8 attention + 200 compute
#define NBLKC  200
#define NTHR   1024
#define TSTEPS 400
#define BATCH  32
#define UNITSN 400
#define NCHARS 73
#define UC     50
#define KTOT   2228   // 476 (z1) + 876 (z2) + 876 (z3)
#define WSTR   2236   // LDS weight row stride (floats); 2236%32=28 -> 8 cols
                      // hit 8 distinct bank quads -> conflict-free b128 reads
#define NGRP   8
#define NFLAG  32
#define NEPOCH 402    // 1 prologue + 400 steps + 1 epilogue

typedef unsigned int       u32;
typedef unsigned long long u64;

// ---- ws byte layout ----
// [0,4096): barrier ints (memset to 0 each launch)
//   grp_cnt[g] at int g*16 (g<8); glob_cnt at int 128; wcnt at int 192;
//   flags[f] at int 256+f*16
#define STATE_BYTES 4096
#define HSLOT     12832                           // fp32 elems/slot (12800+32 pad)
#define H1_BYTE   4096
#define H2_BYTE   (H1_BYTE + TSTEPS * HSLOT * 4)
#define H3_BYTE   (H2_BYTE + TSTEPS * HSLOT * 4)
#define WSLOT     2368                            // fp32 elems/slot (2336+32 pad)
#define WH_BYTE   (H3_BYTE + TSTEPS * HSLOT * 4)
// end of ws usage: WH_BYTE + 400*WSLOT*4 = 65,386,496 bytes (~62 MB)

__device__ __forceinline__ float sigf(float x)   { return 1.0f / (1.0f + __expf(-x)); }
__device__ __forceinline__ float tanhf_(float x) { return 1.0f - 2.0f / (1.0f + __expf(2.0f * x)); }

// single 100-float quarter dot: w from LDS, x from global
__device__ __forceinline__ float dot100(const float* __restrict__ w,
                                        const float* __restrict__ x) {
  const float4* wv = (const float4*)w;
  const float4* xv = (const float4*)x;
  float s0 = 0.f, s1 = 0.f, s2 = 0.f, s3 = 0.f;
#pragma unroll 5
  for (int i = 0; i < 25; ++i) {
    float4 a = wv[i], bb = xv[i];
    s0 = fmaf(a.x, bb.x, s0); s1 = fmaf(a.y, bb.y, s1);
    s2 = fmaf(a.z, bb.z, s2); s3 = fmaf(a.w, bb.w, s3);
  }
  return (s0 + s1) + (s2 + s3);
}

// dual dot sharing one x stream: ra += wa.x, rb += wb.x
__device__ __forceinline__ void dot100x2(const float* __restrict__ wa,
                                         const float* __restrict__ wb,
                                         const float* __restrict__ x,
                                         float& ra, float& rb) {
  const float4* av = (const float4*)wa;
  const float4* bv = (const float4*)wb;
  const float4* xv = (const float4*)x;
  float a0 = 0.f, a1 = 0.f, a2 = 0.f, a3 = 0.f;
  float c0 = 0.f, c1 = 0.f, c2 = 0.f, c3 = 0.f;
#pragma unroll 5
  for (int i = 0; i < 25; ++i) {
    float4 xx = xv[i], aa = av[i], bb = bv[i];
    a0 = fmaf(aa.x, xx.x, a0); a1 = fmaf(aa.y, xx.y, a1);
    a2 = fmaf(aa.z, xx.z, a2); a3 = fmaf(aa.w, xx.w, a3);
    c0 = fmaf(bb.x, xx.x, c0); c1 = fmaf(bb.y, xx.y, c1);
    c2 = fmaf(bb.z, xx.z, c2); c3 = fmaf(bb.w, xx.w, c3);
  }
  ra += (a0 + a1) + (a2 + a3);
  rb += (c0 + c1) + (c2 + c3);
}

// fused P-phase dots (t>=2): three x streams (h2p, h1t, h3pp), five weight
// streams.  r3 += wA.x2 + wE.x3, r2 += wB.x2 + wC.x1, r1 += wD.x1.
__device__ __forceinline__ void dotP3(const float* __restrict__ wA,
                                      const float* __restrict__ wB,
                                      const float* __restrict__ x2,
                                      const float* __restrict__ wC,
                                      const float* __restrict__ wD,
                                      const float* __restrict__ x1,
                                      const float* __restrict__ wE,
                                      const float* __restrict__ x3,
                                      float& r3, float& r2, float& r1) {
  const float4* Av = (const float4*)wA;
  const float4* Bv = (const float4*)wB;
  const float4* Cv = (const float4*)wC;
  const float4* Dv = (const float4*)wD;
  const float4* Ev = (const float4*)wE;
  const float4* x2v = (const float4*)x2;
  const float4* x1v = (const float4*)x1;
  const float4* x3v = (const float4*)x3;
  float sA0 = 0.f, sA1 = 0.f, sA2 = 0.f, sA3 = 0.f;
  float sB0 = 0.f, sB1 = 0.f, sB2 = 0.f, sB3 = 0.f;
  float sC0 = 0.f, sC1 = 0.f, sC2 = 0.f, sC3 = 0.f;
  float sD0 = 0.f, sD1 = 0.f, sD2 = 0.f, sD3 = 0.f;
  float sE0 = 0.f, sE1 = 0.f, sE2 = 0.f, sE3 = 0.f;
#pragma unroll 2
  for (int i = 0; i < 25; ++i) {
    float4 xa = x2v[i], xb = x1v[i], xc = x3v[i];
    float4 a = Av[i], bb = Bv[i], cc = Cv[i], d = Dv[i], e = Ev[i];
    sA0 = fmaf(a.x, xa.x, sA0);  sA1 = fmaf(a.y, xa.y, sA1);
    sA2 = fmaf(a.z, xa.z, sA2);  sA3 = fmaf(a.w, xa.w, sA3);
    sB0 = fmaf(bb.x, xa.x, sB0); sB1 = fmaf(bb.y, xa.y, sB1);
    sB2 = fmaf(bb.z, xa.z, sB2); sB3 = fmaf(bb.w, xa.w, sB3);
    sC0 = fmaf(cc.x, xb.x, sC0); sC1 = fmaf(cc.y, xb.y, sC1);
    sC2 = fmaf(cc.z, xb.z, sC2); sC3 = fmaf(cc.w, xb.w, sC3);
    sD0 = fmaf(d.x, xb.x, sD0);  sD1 = fmaf(d.y, xb.y, sD1);
    sD2 = fmaf(d.z, xb.z, sD2);  sD3 = fmaf(d.w, xb.w, sD3);
    sE0 = fmaf(e.x, xc.x, sE0);  sE1 = fmaf(e.y, xc.y, sE1);
    sE2 = fmaf(e.z, xc.z, sE2);  sE3 = fmaf(e.w, xc.w, sE3);
  }
  r3 += (sA0 + sA1) + (sA2 + sA3) + (sE0 + sE1) + (sE2 + sE3);
  r2 += (sB0 + sB1) + (sB2 + sB3) + (sC0 + sC1) + (sC2 + sC3);
  r1 += (sD0 + sD1) + (sD2 + sD3);
}

// triple 73-float dot sharing one x stream (LDS), K-quarter split {19,18,18,18}
__device__ __forceinline__ void dot73x3(const float* __restrict__ w1,
                                        const float* __restrict__ w2,
                                        const float* __restrict__ w3,
                                        const float* __restrict__ x, int kq,
                                        float& r1, float& r2, float& r3) {
  int st = (kq == 0) ? 0 : 18 * kq + 1;
  int en = st + ((kq == 0) ? 19 : 18);
  float s1 = 0.f, s2 = 0.f, s3 = 0.f;
  for (int k = st; k < en; ++k) {
    float xv = x[k];
    s1 = fmaf(w1[k], xv, s1); s2 = fmaf(w2[k], xv, s2); s3 = fmaf(w3[k], xv, s3);
  }
  r1 += s1; r2 += s2; r3 += s3;
}

extern "C" __global__ void __launch_bounds__(NTHR)
__attribute__((amdgpu_waves_per_eu(4, 4)))
hand_kernel(const float* __restrict__ xs, const int* __restrict__ chars,
            const int* __restrict__ lens,
            const float* __restrict__ Wx0, const float* __restrict__ Wh0,
            const float* __restrict__ b0, const float* __restrict__ p0,
            const float* __restrict__ Wx1, const float* __restrict__ Wh1,
            const float* __restrict__ b1, const float* __restrict__ p1,
            const float* __restrict__ Wx2, const float* __restrict__ Wh2,
            const float* __restrict__ b2, const float* __restrict__ p2,
            const float* __restrict__ Watt, const float* __restrict__ batt,
            const float* __restrict__ Wmdn, const float* __restrict__ bmdn,
            float* __restrict__ dout, char* __restrict__ wsb) {
  const int blk = blockIdx.x;
  const int tid = threadIdx.x;
  const bool is_att = (blk < NATT);
  const int cblk = blk - NATT;        // compute block index 0..199

  __shared__ __align__(16) float wlw[8 * WSTR];   // compute: 71.6KB weights
                                                  // attention: Watt[12000] +
                                                  //   attp[960] partials
  __shared__ float zpart[NTHR], zpartB[NTHR];
  __shared__ float zbuf[256], zbufB[256];
  __shared__ float biasL[3][8];
  __shared__ float peepL[3][3][2];
  __shared__ float cstate[3][64];     // [layer][ul*32 + b]
  __shared__ int   bar_target;
  __shared__ float alphaL[40], betaL[40], kappaL[40];   // attention (4 batches)
  __shared__ float wlds[4 * NCHARS];                    // attention w slice
  __shared__ __align__(16) float wstg[BATCH * NCHARS + 12];  // compute: staged w(t)

  int*   bar_i = (int*)wsb;
  int*   glob  = bar_i + 128;
  int*   wcnt  = bar_i + 192;
  float* h1h   = (float*)(wsb + H1_BYTE);
  float* h2h   = (float*)(wsb + H2_BYTE);
  float* h3h   = (float*)(wsb + H3_BYTE);
  float* whh   = (float*)(wsb + WH_BYTE);

  const int out = tid & 255;
  const int b   = out >> 3;    // batch 0..31
  const int c   = out & 7;     // col: (c>>2)=unit_local, (c&3)=gate (i,f,g,o)
  const int kq  = tid >> 8;    // k-quarter 0..3
  const int u0  = 2 * cblk;    // compute blocks: cols 0..398

  if (tid == 0) bar_target = 0;
  if (tid < 192) cstate[tid / 64][tid % 64] = 0.f;
  if (tid < 40) kappaL[tid] = 0.f;

  // ---- one-time staging ----
  if (!is_att) {
    // compute: 8 weight columns into LDS
    for (int idx = tid; idx < 8 * KTOT; idx += NTHR) {
      int cc = idx / KTOT, k = idx - cc * KTOT;
      int gcol = (cc & 3) * UNITSN + u0 + (cc >> 2);
      float v;
      if (k < 476)        v = (k < 76)  ? Wx0[(size_t)k * 1600 + gcol]
                                        : Wh0[(size_t)(k - 76) * 1600 + gcol];
      else if (k < 1352) { int q = k - 476;
                          v = (q < 476) ? Wx1[(size_t)q * 1600 + gcol]
                                        : Wh1[(size_t)(q - 476) * 1600 + gcol]; }
      else               { int q = k - 1352;
                          v = (q < 476) ? Wx2[(size_t)q * 1600 + gcol]
                                        : Wh2[(size_t)(q - 476) * 1600 + gcol]; }
      wlw[cc * WSTR + k] = v;
    }
    if (tid < 24) {
      int l = tid >> 3, cc = tid & 7;
      const float* bs = (l == 0) ? b0 : (l == 1) ? b1 : b2;
      biasL[l][cc] = bs[(cc & 3) * UNITSN + u0 + (cc >> 2)];
    }
    if (tid < 18) {
      int l = tid / 6, r = (tid % 6) >> 1, ul = tid & 1;
      const float* ps = (l == 0) ? p0 : (l == 1) ? p1 : p2;
      peepL[l][r][ul] = ps[r * UNITSN + u0 + ul];
    }
  } else {
    // attention: Watt[400][30] into LDS (reused all 400 steps)
    for (int i = tid; i < 12000; i += NTHR) wlw[i] = Watt[i];
  }
  __syncthreads();

  const float* Wc   = wlw + c * WSTR;   // compute: this thread's column
  float*       attp = wlw + 12000;      // attention: 960 partials

  // ---- compute-only two-level grid barrier (flag release; verified) ----
  auto gridbar = [&]() {
    __syncthreads();
    if (tid == 0) {
      int e = ++bar_target;
      int g = cblk & (NGRP - 1);
      const int gsz = NBLKC / NGRP;                  // 25 exactly
      int a = __hip_atomic_fetch_add(bar_i + g * 16, 1, __ATOMIC_RELAXED, __HIP_MEMORY_SCOPE_AGENT);
      if (a + 1 == e * gsz) {                        // last of my group this epoch
        int q = __hip_atomic_fetch_add(glob, 1, __ATOMIC_RELAXED, __HIP_MEMORY_SCOPE_AGENT);
        if (((q + 1) & (NGRP - 1)) == 0) {           // last group: release all
          for (int f = 0; f < NFLAG; ++f)
            __hip_atomic_store(bar_i + 256 + f * 16, e, __ATOMIC_RELAXED, __HIP_MEMORY_SCOPE_AGENT);
        }
      }
      int* myflag = bar_i + 256 + (cblk & (NFLAG - 1)) * 16;
      while (__hip_atomic_load(myflag, __ATOMIC_RELAXED, __HIP_MEMORY_SCOPE_AGENT) < e)
        __builtin_amdgcn_s_sleep(1);
    }
    __syncthreads();
  };

  // attention-side wait: poll the glob group-counter (8 pollers only);
  // glob reaches NGRP*e when compute epoch e is fully arrived.
  auto waitglob = [&](int e) {
    if (tid == 0) {
      int tgt = NGRP * e;
      while (__hip_atomic_load(glob, __ATOMIC_RELAXED, __HIP_MEMORY_SCOPE_AGENT) < tgt)
        __builtin_amdgcn_s_sleep(1);
    }
    __syncthreads();
  };

  // gate math for one layer, 2 units, one 8B write-through store
  auto gates = [&](int layer, const float* zb, int bb, float* hdst) {
    union { float f[2]; u64 v; } pk;
#pragma unroll
    for (int ul = 0; ul < 2; ++ul) {
      float zi = zb[bb * 8 + ul * 4 + 0], zf = zb[bb * 8 + ul * 4 + 1];
      float zg = zb[bb * 8 + ul * 4 + 2], zo = zb[bb * 8 + ul * 4 + 3];
      float cold = cstate[layer][ul * 32 + bb];
      float ig = sigf(zi + peepL[layer][0][ul] * cold);
      float fg = sigf(zf + peepL[layer][1][ul] * cold);
      float cn = fg * cold + ig * tanhf_(zg);
      float og = sigf(zo + peepL[layer][2][ul] * cn);
      cstate[layer][ul * 32 + bb] = cn;
      pk.f[ul] = og * tanhf_(cn);
    }
    __hip_atomic_store((u64*)(hdst + bb * UNITSN + u0), pk.v,
                       __ATOMIC_RELAXED, __HIP_MEMORY_SCOPE_AGENT);
  };

  // single-layer finalize; NO trailing sync
  auto finalize1 = [&](int layer, float acc, float* hdst) {
    zpart[tid] = acc;
    __syncthreads();
    if (tid < 256)
      zbuf[tid] = zpart[tid] + zpart[tid + 256] + zpart[tid + 512] + zpart[tid + 768]
                + biasL[layer][tid & 7];
    __syncthreads();
    if (tid < 256 && (tid & 7) == 0) gates(layer, zbuf, tid >> 3, hdst);
  };

  // merged Q finalize: h2(t) and (optionally) h1(t+1); NO trailing sync
  auto finalizeQ = [&](float a2v, float* h2dst, float a1v, float* h1dst, bool do1) {
    zpart[tid]  = a2v;
    zpartB[tid] = a1v;
    __syncthreads();
    if (tid < 256) {
      zbuf[tid]  = zpart[tid]  + zpart[tid + 256]  + zpart[tid + 512]  + zpart[tid + 768]
                 + biasL[1][tid & 7];
      zbufB[tid] = zpartB[tid] + zpartB[tid + 256] + zpartB[tid + 512] + zpartB[tid + 768]
                 + biasL[0][tid & 7];
    }
    __syncthreads();
    if (tid < 256 && (tid & 7) == 0) {
      gates(1, zbuf, tid >> 3, h2dst);
      if (do1) gates(0, zbufB, tid >> 3, h1dst);
    }
  };

  // ============================ ATTENTION PATH ============================
  if (is_att) {
    const int bs0 = blk * 4;
    for (int t = 0; t < TSTEPS; ++t) {
      waitglob(t + 1);                       // h1(t) certified by epoch t+1
      const float* h1g = h1h + (size_t)t * HSLOT;
      float* wdst = whh + (size_t)t * WSLOT + bs0 * NCHARS;
      for (int i = tid; i < 4 * NCHARS; i += NTHR) wlds[i] = 0.f;
      // stage B: 2b x 2j x 8ks register tile; h float2-vectorized
      if (tid < 240) {
        int ks = tid / 30, r = tid - ks * 30;
        int bb2 = r / 15, jj2 = r - bb2 * 15;
        int j0 = 2 * jj2, j1 = j0 + 1;
        const float2* h0v = (const float2*)(h1g + (bs0 + 2 * bb2) * UNITSN + ks * 50);
        const float2* h1v = (const float2*)(h1g + (bs0 + 2 * bb2 + 1) * UNITSN + ks * 50);
        const float* wv = wlw + (ks * 50) * 30;
        float s00 = 0.f, s01 = 0.f, s10 = 0.f, s11 = 0.f;
#pragma unroll
        for (int kk = 0; kk < 25; ++kk) {
          float2 ha = h0v[kk], hb = h1v[kk];
          float wa0 = wv[(2 * kk) * 30 + j0],     wb0 = wv[(2 * kk) * 30 + j1];
          float wa1 = wv[(2 * kk + 1) * 30 + j0], wb1 = wv[(2 * kk + 1) * 30 + j1];
          s00 = fmaf(ha.x, wa0, s00); s01 = fmaf(ha.x, wb0, s01);
          s10 = fmaf(hb.x, wa0, s10); s11 = fmaf(hb.x, wb0, s11);
          s00 = fmaf(ha.y, wa1, s00); s01 = fmaf(ha.y, wb1, s01);
          s10 = fmaf(hb.y, wa1, s10); s11 = fmaf(hb.y, wb1, s11);
        }
        int b0i = 2 * bb2;
        attp[(b0i * 30 + j0) * 8 + ks] = s00;
        attp[(b0i * 30 + j1) * 8 + ks] = s01;
        attp[((b0i + 1) * 30 + j0) * 8 + ks] = s10;
        attp[((b0i + 1) * 30 + j1) * 8 + ks] = s11;
      }
      __syncthreads();
      // reduce 8 partials + transforms (40 threads: bl 0..3, j 0..9)
      if (tid < 40) {
        int bl = tid / 10, j = tid - bl * 10;
        float ah = batt[j], bh = batt[10 + j], kh = batt[20 + j];
#pragma unroll
        for (int s = 0; s < 8; ++s) {
          ah += attp[(bl * 30 + j) * 8 + s];
          bh += attp[(bl * 30 + 10 + j) * 8 + s];
          kh += attp[(bl * 30 + 20 + j) * 8 + s];
        }
        float kap = kappaL[tid] + __expf(kh);
        kappaL[tid] = kap;
        alphaL[tid] = __expf(ah);
        betaL[tid]  = __expf(bh);
      }
      __syncthreads();
      // phi + soft window scatter (200 items, few LDS atomics)
      if (tid < 4 * UC) {
        int bl = tid / UC, u = tid - bl * UC;
        if (u < lens[bs0 + bl]) {
          float ph = 0.f;
#pragma unroll
          for (int j = 0; j < 10; ++j) {
            float d = kappaL[bl * 10 + j] - (float)u;
            ph = fmaf(alphaL[bl * 10 + j], __expf(-betaL[bl * 10 + j] * d * d), ph);
          }
          atomicAdd(&wlds[bl * NCHARS + chars[(bs0 + bl) * UC + u]], ph);
        }
      }
      __syncthreads();
      // write w slice (292 floats = 146 u64 write-through stores)
      for (int i = tid; i < (4 * NCHARS) / 2; i += NTHR) {
        union { float f[2]; u64 v; } pk;
        pk.f[0] = wlds[2 * i]; pk.f[1] = wlds[2 * i + 1];
        __hip_atomic_store((u64*)(wdst + 2 * i), pk.v,
                           __ATOMIC_RELAXED, __HIP_MEMORY_SCOPE_AGENT);
      }
      __syncthreads();   // drain all waves' write-through stores
      if (tid == 0)
        __hip_atomic_fetch_add(wcnt, 1, __ATOMIC_RELAXED, __HIP_MEMORY_SCOPE_AGENT);
    }
    waitglob(NEPOCH);    // h3(T-1) certified before MDN
  }
  // ============================ COMPUTE PATH =============================
  else {
    // prologue: h1(0) from x(0) only -> h1 slot 0
    {
      float acc = 0.f;
      if (kq == 0) {
        const float* xr = xs + (size_t)b * TSTEPS * 3;
        acc = Wc[0] * xr[0] + Wc[1] * xr[1] + Wc[2] * xr[2];
      }
      finalize1(0, acc, h1h);
    }
    gridbar();                                        // epoch 1

    float acc_z3 = 0.f;
    for (int t = 0; t < TSTEPS; ++t) {
      const float* h1t  = h1h + (size_t)t * HSLOT + b * UNITSN;
      const float* h2p  = h2h + (size_t)(t > 0 ? t - 1 : 0) * HSLOT + b * UNITSN;
      const float* h3pp = h3h + (size_t)(t > 1 ? t - 2 : 0) * HSLOT + b * UNITSN;
      // ---- P: h-dots ----
      const int o = kq * 100;
      float a3f = acc_z3, a2 = 0.f, a1 = 0.f;
      if (t >= 2) {
        dotP3(Wc + 1428 + o, Wc + 952 + o, h2p + o,
              Wc + 552 + o,  Wc + 76 + o,  h1t + o,
              Wc + 1828 + o, h3pp + o, a3f, a2, a1);
      } else if (t == 1) {
        dot100x2(Wc + 1428 + o, Wc + 952 + o, h2p + o, a3f, a2);
        dot100x2(Wc + 552 + o, Wc + 76 + o, h1t + o, a2, a1);
      } else {
        dot100x2(Wc + 552 + o, Wc + 76 + o, h1t + o, a2, a1);
      }
      if (kq == 0) {
        const float* xr = xs + ((size_t)b * TSTEPS + t) * 3;
        a2 += Wc[476] * xr[0] + Wc[477] * xr[1] + Wc[478] * xr[2];
        if (t < TSTEPS - 1)
          a1 += Wc[0] * xr[3] + Wc[1] * xr[4] + Wc[2] * xr[5];
      }
      // finalize h3(t-1) here: overlaps the w-wait window (round-6 ordering)
      if (t > 0) finalize1(2, a3f, h3h + (size_t)(t - 1) * HSLOT);
      // ---- wait for w(t) (monotone counter) ----
      if (tid == 0) {
        int tgt = NATT * (t + 1);
        while (__hip_atomic_load(wcnt, __ATOMIC_RELAXED, __HIP_MEMORY_SCOPE_AGENT) < tgt)
          __builtin_amdgcn_s_sleep(1);
      }
      __syncthreads();
      // ---- stage w(t) into LDS (584 coalesced float4) ----
      {
        const float4* wsrc = (const float4*)(whh + (size_t)t * WSLOT);
        for (int i = tid; i < (BATCH * NCHARS) / 4; i += NTHR)
          ((float4*)wstg)[i] = wsrc[i];
      }
      __syncthreads();
      // ---- Q: w-dots + finalize h2(t), h1(t+1) ----
      bool do1 = (t < TSTEPS - 1);
      float q2 = a2, q1 = a1, z3n = 0.f;
      dot73x3(Wc + 479, Wc + 3, Wc + 1355, wstg + b * NCHARS, kq, q2, q1, z3n);
      if (kq == 0) {
        const float* xr = xs + ((size_t)b * TSTEPS + t) * 3;
        z3n += Wc[1352] * xr[0] + Wc[1353] * xr[1] + Wc[1354] * xr[2];
      }
      finalizeQ(q2, h2h + (size_t)t * HSLOT,
                q1, h1h + (size_t)(t + 1) * HSLOT, do1);
      acc_z3 = z3n;
      gridbar();                                      // epoch t+2
    }
    // epilogue: finish z3(T-1) -> h3 slot T-1
    {
      const float* h2l  = h2h + (size_t)(TSTEPS - 1) * HSLOT + b * UNITSN;
      const float* h3ll = h3h + (size_t)(TSTEPS - 2) * HSLOT + b * UNITSN;
      float a3 = acc_z3 + dot100(Wc + 1428 + kq * 100, h2l + kq * 100)
                        + dot100(Wc + 1828 + kq * 100, h3ll + kq * 100);
      finalize1(2, a3, h3h + (size_t)(TSTEPS - 1) * HSLOT);
    }
    gridbar();                                        // epoch 402
  }

  // ---- MDN head + output transforms (parallel over 12800 (b,t) rows) ----
  {
    int j = tid & 127, ks = tid >> 7;   // 8 k-slices of 50
    for (int i0 = 0; i0 < 64; i0 += 4) {
      float acc[4] = {0.f, 0.f, 0.f, 0.f};
      const float* hp[4];
      bool val[4];
      for (int r = 0; r < 4; ++r) {
        int row = blk + (i0 + r) * NBLK;
        val[r] = (row < 12800);
        hp[r] = val[r] ? (h3h + (size_t)(row % TSTEPS) * HSLOT + (row / TSTEPS) * UNITSN + ks * 50)
                       : h3h;
      }
      if (j < 121) {
        const float* wp = Wmdn + (size_t)(ks * 50) * 121 + j;
        for (int k = 0; k < 50; ++k) {
          float wv = wp[(size_t)k * 121];
#pragma unroll
          for (int r = 0; r < 4; ++r) acc[r] = fmaf(hp[r][k], wv, acc[r]);
        }
      }
      for (int r = 0; r < 4; ++r) {
        zpart[tid] = acc[r];
        __syncthreads();
        if (tid < 121) {
          float s = bmdn[tid];
#pragma unroll
          for (int m = 0; m < 8; ++m) s += zpart[tid + m * 128];
          zbuf[tid] = s;
        }
        __syncthreads();
        if (tid == 0) {
          float mx = zbuf[0];
          for (int q = 1; q < 20; ++q) mx = fmaxf(mx, zbuf[q]);
          float s = 0.f;
          for (int q = 0; q < 20; ++q) s += __expf(zbuf[q] - mx);
          zbuf[126] = mx;
          zbuf[127] = 1.f / s;
        }
        __syncthreads();
        if (val[r] && tid < 121) {
          int row = blk + (i0 + r) * NBLK;
          float y = zbuf[tid], o;
          if (tid < 20)       o = __expf(y - zbuf[126]) * zbuf[127];  // softmax(pi)
          else if (tid < 60)  o = y;                                   // mu1, mu2
          else if (tid < 100) o = __expf(y);                           // s1, s2
          else if (tid < 120) o = tanhf_(y);                           // rho
          else                o = sigf(y);                             // eos
          dout[(size_t)row * 121 + tid] = o;
        }
        __syncthreads();
      }
    }
  }
}

extern "C" void kernel_launch(void* const* d_in, const int* in_sizes, int n_in,
                              void* d_out, int out_size, void* d_ws, size_t ws_size,
                              hipStream_t stream) {
  const float* xs   = (const float*)d_in[0];
  const int*   chrs = (const int*)d_in[1];
  const int*   lens = (const int*)d_in[2];
  const float* Wx0  = (const float*)d_in[3];
  const float* Wh0  = (const float*)d_in[4];
  const float* b0   = (const float*)d_in[5];
  const float* p0   = (const float*)d_in[6];
  const float* Wx1  = (const float*)d_in[7];
  const float* Wh1  = (const float*)d_in[8];
  const float* b1   = (const float*)d_in[9];
  const float* p1   = (const float*)d_in[10];
  const float* Wx2  = (const float*)d_in[11];
  const float* Wh2  = (const float*)d_in[12];
  const float* b2   = (const float*)d_in[13];
  const float* p2   = (const float*)d_in[14];
  const float* Watt = (const float*)d_in[15];
  const float* batt = (const float*)d_in[16];
  const float* Wmdn = (const float*)d_in[17];
  const float* bmdn = (const float*)d_in[18];

  // zero barrier counters/flags + wcnt (4KB); everything else is write-once
  hipMemsetAsync(d_ws, 0, STATE_BYTES, stream);
  hipLaunchKernelGGL(hand_kernel, dim3(NBLK), dim3(NTHR), 0, stream,
                     xs, chrs, lens, Wx0, Wh0, b0, p0, Wx1, Wh1, b1, p1,
                     Wx2, Wh2, b2, p2, Watt, batt, Wmdn, bmdn,
                     (float*)d_out, (char*)d_ws);
}